// Round 5
// baseline (540.495 us; speedup 1.0000x reference)
//
#include <hip/hip_runtime.h>
#include <hip/hip_fp16.h>
#include <hip/hip_cooperative_groups.h>

namespace cg = cooperative_groups;

#define SAMPLES 32
#define ELEMS_PER_SAMPLE (256 * 64 * 64)              // 1048576
#define VEC4_PER_SAMPLE (ELEMS_PER_SAMPLE / 4)        // 262144
#define THREADS 256

// Cooperative config: 1024 blocks co-resident (4/CU at <=128 VGPR)
#define CBLOCKS 1024
#define CBLOCKS_PER_SAMPLE (CBLOCKS / SAMPLES)        // 32
#define VEC4_PER_THREAD (VEC4_PER_SAMPLE * SAMPLES / (CBLOCKS * THREADS))  // 32

// Fallback (non-cooperative) config
#define FGRID 2048
#define FBLOCKS_PER_SAMPLE 64
#define FITERS (VEC4_PER_SAMPLE / (FBLOCKS_PER_SAMPLE * THREADS))  // 16

#define BETA 2.0f
#define EPS 1e-5f

typedef float f32x4 __attribute__((ext_vector_type(4)));
typedef _Float16 f16x4 __attribute__((ext_vector_type(4)));

__device__ __forceinline__ float wave_reduce_sum(float v) {
#pragma unroll
    for (int off = 32; off > 0; off >>= 1)
        v += __shfl_down(v, off, 64);
    return v;
}

__device__ __forceinline__ float smooth_l1(float d) {
    return (d <= BETA) ? (0.25f * d * d) : (d - 1.0f);
}

// Block-level reduce of one float; result valid in thread 0.
__device__ __forceinline__ float block_reduce(float v, float* sm) {
    const int lane = threadIdx.x & 63;
    const int wid = threadIdx.x >> 6;
    v = wave_reduce_sum(v);
    if (lane == 0) sm[wid] = v;
    __syncthreads();
    float r = 0.0f;
    if (threadIdx.x == 0) r = sm[0] + sm[1] + sm[2] + sm[3];
    __syncthreads();
    return r;
}

// ws layout (floats):
//   [0 .. 2*CBLOCKS)            per-block (sum, sumsq)
//   [2*CBLOCKS .. 3*CBLOCKS)    per-block loss partials
// (fallback path uses the same regions with FGRID strides; ws >= 3*FGRID floats)

// ================= cooperative fused kernel =================
__global__ __launch_bounds__(THREADS, 4) void kd_fused_kernel(
    const f32x4* __restrict__ t, const f32x4* __restrict__ st,
    float* __restrict__ ws, float* __restrict__ out) {
    __shared__ float sm[2 * (THREADS / 64)];
    const size_t base = (size_t)blockIdx.x * (THREADS * VEC4_PER_THREAD);

    // ---- Phase 1: read teacher once; keep fp16 copy in registers ----
    f16x4 keep[VEC4_PER_THREAD];
    float sum = 0.0f, sumsq = 0.0f;
#pragma unroll
    for (int i = 0; i < VEC4_PER_THREAD; ++i) {
        f32x4 v = __builtin_nontemporal_load(t + base + i * THREADS + threadIdx.x);
        sum += v.x + v.y + v.z + v.w;
        sumsq += v.x * v.x + v.y * v.y + v.z * v.z + v.w * v.w;
        f16x4 h;
        h.x = (_Float16)v.x; h.y = (_Float16)v.y;
        h.z = (_Float16)v.z; h.w = (_Float16)v.w;
        keep[i] = h;
    }

    {
        const int lane = threadIdx.x & 63;
        const int wid = threadIdx.x >> 6;
        float s1 = wave_reduce_sum(sum);
        float s2 = wave_reduce_sum(sumsq);
        if (lane == 0) {
            sm[wid] = s1;
            sm[(THREADS / 64) + wid] = s2;
        }
        __syncthreads();
        if (threadIdx.x == 0) {
            ws[2 * blockIdx.x]     = sm[0] + sm[1] + sm[2] + sm[3];
            ws[2 * blockIdx.x + 1] = sm[4] + sm[5] + sm[6] + sm[7];
        }
    }

    __threadfence();
    cg::this_grid().sync();

    // ---- Phase 2: per-sample stats from partials (L2-hot), then loss ----
    const int s = blockIdx.x / CBLOCKS_PER_SAMPLE;
    const int lane = threadIdx.x & 63;
    float ps = 0.0f, pq = 0.0f;
    if (lane < CBLOCKS_PER_SAMPLE) {
        ps = ws[2 * (s * CBLOCKS_PER_SAMPLE + lane)];
        pq = ws[2 * (s * CBLOCKS_PER_SAMPLE + lane) + 1];
    }
    ps = wave_reduce_sum(ps);
    pq = wave_reduce_sum(pq);
    ps = __shfl(ps, 0, 64);
    pq = __shfl(pq, 0, 64);

    const float inv_n = 1.0f / (float)ELEMS_PER_SAMPLE;
    const float mean = ps * inv_n;
    const float var = pq * inv_n - mean * mean;
    const float rstd = rsqrtf(var + EPS);

    float acc = 0.0f;
#pragma unroll
    for (int i = 0; i < VEC4_PER_THREAD; ++i) {
        f32x4 sv = __builtin_nontemporal_load(st + base + i * THREADS + threadIdx.x);
        f16x4 h = keep[i];
        float d0 = fabsf(((float)h.x - mean) * rstd - sv.x);
        float d1 = fabsf(((float)h.y - mean) * rstd - sv.y);
        float d2 = fabsf(((float)h.z - mean) * rstd - sv.z);
        float d3 = fabsf(((float)h.w - mean) * rstd - sv.w);
        acc += smooth_l1(d0) + smooth_l1(d1) + smooth_l1(d2) + smooth_l1(d3);
    }

    {
        float b = block_reduce(acc, sm);
        if (threadIdx.x == 0) ws[2 * CBLOCKS + blockIdx.x] = b;
    }

    __threadfence();
    cg::this_grid().sync();

    // ---- Phase 3: block 0 reduces the CBLOCKS loss partials ----
    if (blockIdx.x == 0) {
        float a = 0.0f;
#pragma unroll
        for (int i = 0; i < CBLOCKS / THREADS; ++i)  // 4
            a += ws[2 * CBLOCKS + i * THREADS + threadIdx.x];
        float tot = block_reduce(a, sm);
        if (threadIdx.x == 0) out[0] = tot * (1.0f / (float)SAMPLES);
    }
}

// ================= fallback path (round-2 structure) =================
__global__ __launch_bounds__(THREADS) void kd_stats_kernel(
    const f32x4* __restrict__ t, float* __restrict__ stats) {
    const size_t base = (size_t)blockIdx.x * (THREADS * FITERS);
    float sum = 0.0f, sumsq = 0.0f;
#pragma unroll
    for (int i = 0; i < FITERS; ++i) {
        f32x4 v = t[base + i * THREADS + threadIdx.x];
        sum += v.x + v.y + v.z + v.w;
        sumsq += v.x * v.x + v.y * v.y + v.z * v.z + v.w * v.w;
    }
    const int lane = threadIdx.x & 63;
    const int wid = threadIdx.x >> 6;
    sum = wave_reduce_sum(sum);
    sumsq = wave_reduce_sum(sumsq);
    __shared__ float sm[2 * (THREADS / 64)];
    if (lane == 0) {
        sm[wid] = sum;
        sm[(THREADS / 64) + wid] = sumsq;
    }
    __syncthreads();
    if (threadIdx.x == 0) {
        stats[2 * blockIdx.x]     = sm[0] + sm[1] + sm[2] + sm[3];
        stats[2 * blockIdx.x + 1] = sm[4] + sm[5] + sm[6] + sm[7];
    }
}

__global__ __launch_bounds__(THREADS) void kd_loss_kernel(
    const f32x4* __restrict__ t, const f32x4* __restrict__ st,
    const float* __restrict__ stats, float* __restrict__ lpart) {
    const int s = blockIdx.x / FBLOCKS_PER_SAMPLE;
    const int lane = threadIdx.x & 63;
    float psum = stats[2 * (s * FBLOCKS_PER_SAMPLE + lane)];
    float psumsq = stats[2 * (s * FBLOCKS_PER_SAMPLE + lane) + 1];
    psum = wave_reduce_sum(psum);
    psumsq = wave_reduce_sum(psumsq);
    psum = __shfl(psum, 0, 64);
    psumsq = __shfl(psumsq, 0, 64);

    const float inv_n = 1.0f / (float)ELEMS_PER_SAMPLE;
    const float mean = psum * inv_n;
    const float var = psumsq * inv_n - mean * mean;
    const float rstd = rsqrtf(var + EPS);

    const size_t base = (size_t)blockIdx.x * (THREADS * FITERS);
    float acc = 0.0f;
#pragma unroll
    for (int i = 0; i < FITERS; ++i) {
        const size_t idx = base + i * THREADS + threadIdx.x;
        f32x4 tv = t[idx];
        f32x4 sv = __builtin_nontemporal_load(st + idx);
        float d0 = fabsf((tv.x - mean) * rstd - sv.x);
        float d1 = fabsf((tv.y - mean) * rstd - sv.y);
        float d2 = fabsf((tv.z - mean) * rstd - sv.z);
        float d3 = fabsf((tv.w - mean) * rstd - sv.w);
        acc += smooth_l1(d0) + smooth_l1(d1) + smooth_l1(d2) + smooth_l1(d3);
    }

    __shared__ float sm[2 * (THREADS / 64)];
    float b = block_reduce(acc, sm);
    if (threadIdx.x == 0) lpart[blockIdx.x] = b;
}

__global__ __launch_bounds__(THREADS) void kd_final_kernel(
    const float* __restrict__ lpart, float* __restrict__ out) {
    float acc = 0.0f;
#pragma unroll
    for (int i = 0; i < FGRID / THREADS; ++i)  // 8
        acc += lpart[i * THREADS + threadIdx.x];
    __shared__ float sm[2 * (THREADS / 64)];
    float tot = block_reduce(acc, sm);
    if (threadIdx.x == 0) out[0] = tot * (1.0f / (float)SAMPLES);
}

extern "C" void kernel_launch(void* const* d_in, const int* in_sizes, int n_in,
                              void* d_out, int out_size, void* d_ws,
                              size_t ws_size, hipStream_t stream) {
    const f32x4* teacher = (const f32x4*)d_in[0];
    const f32x4* student = (const f32x4*)d_in[1];
    float* out = (float*)d_out;
    float* ws = (float*)d_ws;

    void* args[4] = {(void*)&teacher, (void*)&student, (void*)&ws, (void*)&out};
    hipError_t e = hipLaunchCooperativeKernel(
        (void*)kd_fused_kernel, dim3(CBLOCKS), dim3(THREADS), args, 0, stream);

    if (e != hipSuccess) {
        // Fallback: non-cooperative 3-kernel path (round-2 structure)
        float* stats = ws;
        float* lpart = ws + 2 * FGRID;
        kd_stats_kernel<<<FGRID, THREADS, 0, stream>>>(teacher, stats);
        kd_loss_kernel<<<FGRID, THREADS, 0, stream>>>(teacher, student, stats, lpart);
        kd_final_kernel<<<1, THREADS, 0, stream>>>(lpart, out);
    }
}

// Round 6
// 358.524 us; speedup vs baseline: 1.5076x; 1.5076x over previous
//
#include <hip/hip_runtime.h>
#include <hip/hip_fp16.h>
#include <hip/hip_cooperative_groups.h>

namespace cg = cooperative_groups;

#define SAMPLES 32
#define ELEMS_PER_SAMPLE (256 * 64 * 64)              // 1048576
#define VEC4_PER_SAMPLE (ELEMS_PER_SAMPLE / 4)        // 262144
#define THREADS 256

// ---- cooperative fused config: 1024 blocks, 4/CU co-resident ----
#define GRID2 1024
#define BPS2 (GRID2 / SAMPLES)                        // 32 blocks/sample
#define IT2 (VEC4_PER_SAMPLE * SAMPLES / (GRID2 * THREADS))  // 32 f32x4/thread
#define LDS_IT 19                                     // f16x4 iters kept in LDS
#define REG_IT (IT2 - LDS_IT)                         // 13 f16x4 iters in VGPRs

// ---- fallback (round-2) config ----
#define FGRID 2048
#define FBPS 64
#define FITERS (VEC4_PER_SAMPLE / (FBPS * THREADS))   // 16

#define BETA 2.0f
#define EPS 1e-5f

typedef float f32x4 __attribute__((ext_vector_type(4)));
typedef _Float16 f16x4 __attribute__((ext_vector_type(4)));

__device__ __forceinline__ float wave_reduce_sum(float v) {
#pragma unroll
    for (int off = 32; off > 0; off >>= 1)
        v += __shfl_down(v, off, 64);
    return v;
}

__device__ __forceinline__ float smooth_l1(float d) {
    return (d <= BETA) ? (0.25f * d * d) : (d - 1.0f);
}

// ws layout (floats):
//   coop:     [0..2*GRID2) stats pairs | [2*GRID2..3*GRID2) lpart | [3*GRID2] ctr
//   fallback: [0..2*FGRID) stats pairs | [2*FGRID..3*FGRID) lpart
#define W_LPART (2 * GRID2)
#define W_CTR (3 * GRID2)

// ================= cooperative fused kernel =================
__global__ __launch_bounds__(THREADS, 4)
__attribute__((amdgpu_waves_per_eu(4, 4)))
void kd_fused2_kernel(const f32x4* __restrict__ t, const f32x4* __restrict__ st,
                      float* __restrict__ ws, float* __restrict__ out) {
    __shared__ f16x4 lds_keep[LDS_IT * THREADS];  // 38912 B: per-thread arena
    __shared__ float sm[2 * (THREADS / 64)];
    const int tid = threadIdx.x;
    const size_t base = (size_t)blockIdx.x * (THREADS * IT2);

    // ---- Phase A: read teacher ONCE (nt); fp16 copy -> LDS + regs; stats ----
    float sum = 0.0f, sumsq = 0.0f;
    f16x4 keep[REG_IT];
#pragma unroll
    for (int i = 0; i < LDS_IT; ++i) {
        f32x4 v = __builtin_nontemporal_load(t + base + i * THREADS + tid);
        sum += v.x + v.y + v.z + v.w;
        sumsq += v.x * v.x + v.y * v.y + v.z * v.z + v.w * v.w;
        f16x4 h;
        h.x = (_Float16)v.x; h.y = (_Float16)v.y;
        h.z = (_Float16)v.z; h.w = (_Float16)v.w;
        lds_keep[i * THREADS + tid] = h;
    }
#pragma unroll
    for (int i = 0; i < REG_IT; ++i) {
        f32x4 v = __builtin_nontemporal_load(t + base + (LDS_IT + i) * THREADS + tid);
        sum += v.x + v.y + v.z + v.w;
        sumsq += v.x * v.x + v.y * v.y + v.z * v.z + v.w * v.w;
        f16x4 h;
        h.x = (_Float16)v.x; h.y = (_Float16)v.y;
        h.z = (_Float16)v.z; h.w = (_Float16)v.w;
        keep[i] = h;
    }

    {
        const int lane = tid & 63;
        const int wid = tid >> 6;
        float s1 = wave_reduce_sum(sum);
        float s2 = wave_reduce_sum(sumsq);
        if (lane == 0) {
            sm[wid] = s1;
            sm[(THREADS / 64) + wid] = s2;
        }
        __syncthreads();
        if (tid == 0) {
            ws[2 * blockIdx.x]     = sm[0] + sm[1] + sm[2] + sm[3];
            ws[2 * blockIdx.x + 1] = sm[4] + sm[5] + sm[6] + sm[7];
            if (blockIdx.x == 0) *(volatile unsigned*)&ws[W_CTR] = 0u;  // reset ctr (poison/replay-safe)
        }
    }

    __threadfence();
    cg::this_grid().sync();

    // ---- Phase B: per-sample stats from partials, then loss vs student ----
    const int s = blockIdx.x / BPS2;
    const int lane = tid & 63;
    float ps = 0.0f, pq = 0.0f;
    if (lane < BPS2) {
        ps = ws[2 * (s * BPS2 + lane)];
        pq = ws[2 * (s * BPS2 + lane) + 1];
    }
    ps = wave_reduce_sum(ps);
    pq = wave_reduce_sum(pq);
    ps = __shfl(ps, 0, 64);
    pq = __shfl(pq, 0, 64);

    const float inv_n = 1.0f / (float)ELEMS_PER_SAMPLE;
    const float mean = ps * inv_n;
    const float var = pq * inv_n - mean * mean;
    const float rstd = rsqrtf(var + EPS);
    const float nb = -mean * rstd;  // t_norm = fma(t, rstd, nb)

    float acc = 0.0f;
#pragma unroll
    for (int i = 0; i < LDS_IT; ++i) {
        f32x4 sv = __builtin_nontemporal_load(st + base + i * THREADS + tid);
        f16x4 h = lds_keep[i * THREADS + tid];
        float d0 = fabsf(fmaf((float)h.x, rstd, nb) - sv.x);
        float d1 = fabsf(fmaf((float)h.y, rstd, nb) - sv.y);
        float d2 = fabsf(fmaf((float)h.z, rstd, nb) - sv.z);
        float d3 = fabsf(fmaf((float)h.w, rstd, nb) - sv.w);
        acc += smooth_l1(d0) + smooth_l1(d1) + smooth_l1(d2) + smooth_l1(d3);
    }
#pragma unroll
    for (int i = 0; i < REG_IT; ++i) {
        f32x4 sv = __builtin_nontemporal_load(st + base + (LDS_IT + i) * THREADS + tid);
        f16x4 h = keep[i];
        float d0 = fabsf(fmaf((float)h.x, rstd, nb) - sv.x);
        float d1 = fabsf(fmaf((float)h.y, rstd, nb) - sv.y);
        float d2 = fabsf(fmaf((float)h.z, rstd, nb) - sv.z);
        float d3 = fabsf(fmaf((float)h.w, rstd, nb) - sv.w);
        acc += smooth_l1(d0) + smooth_l1(d1) + smooth_l1(d2) + smooth_l1(d3);
    }

    // per-block loss partial
    {
        const int wid = tid >> 6;
        float a = wave_reduce_sum(acc);
        __syncthreads();  // sm reuse safety
        if (lane == 0) sm[wid] = a;
        __syncthreads();
        if (tid == 0) ws[W_LPART + blockIdx.x] = sm[0] + sm[1] + sm[2] + sm[3];
    }

    // ---- last block reduces all partials ----
    __shared__ bool last;
    if (tid == 0) {
        __threadfence();
        unsigned old = atomicAdd((unsigned*)&ws[W_CTR], 1u);
        last = (old == GRID2 - 1);
    }
    __syncthreads();
    if (last) {
        __threadfence();
        float a = 0.0f;
#pragma unroll
        for (int i = 0; i < GRID2 / THREADS; ++i)  // 4
            a += ws[W_LPART + i * THREADS + tid];
        const int wid = tid >> 6;
        a = wave_reduce_sum(a);
        __syncthreads();
        if (lane == 0) sm[wid] = a;
        __syncthreads();
        if (tid == 0)
            out[0] = (sm[0] + sm[1] + sm[2] + sm[3]) * (1.0f / (float)SAMPLES);
    }
}

// ================= fallback path (round-2 structure, 64.5 us) =================
__global__ __launch_bounds__(THREADS) void kd_stats_kernel(
    const f32x4* __restrict__ t, float* __restrict__ stats) {
    const size_t base = (size_t)blockIdx.x * (THREADS * FITERS);
    float sum = 0.0f, sumsq = 0.0f;
#pragma unroll
    for (int i = 0; i < FITERS; ++i) {
        f32x4 v = t[base + i * THREADS + threadIdx.x];
        sum += v.x + v.y + v.z + v.w;
        sumsq += v.x * v.x + v.y * v.y + v.z * v.z + v.w * v.w;
    }
    const int lane = threadIdx.x & 63;
    const int wid = threadIdx.x >> 6;
    sum = wave_reduce_sum(sum);
    sumsq = wave_reduce_sum(sumsq);
    __shared__ float sm[2 * (THREADS / 64)];
    if (lane == 0) {
        sm[wid] = sum;
        sm[(THREADS / 64) + wid] = sumsq;
    }
    __syncthreads();
    if (threadIdx.x == 0) {
        stats[2 * blockIdx.x]     = sm[0] + sm[1] + sm[2] + sm[3];
        stats[2 * blockIdx.x + 1] = sm[4] + sm[5] + sm[6] + sm[7];
    }
}

__global__ __launch_bounds__(THREADS) void kd_loss_kernel(
    const f32x4* __restrict__ t, const f32x4* __restrict__ st,
    const float* __restrict__ stats, float* __restrict__ lpart) {
    const int s = blockIdx.x / FBPS;
    const int lane = threadIdx.x & 63;
    float psum = stats[2 * (s * FBPS + lane)];
    float psumsq = stats[2 * (s * FBPS + lane) + 1];
    psum = wave_reduce_sum(psum);
    psumsq = wave_reduce_sum(psumsq);
    psum = __shfl(psum, 0, 64);
    psumsq = __shfl(psumsq, 0, 64);

    const float inv_n = 1.0f / (float)ELEMS_PER_SAMPLE;
    const float mean = psum * inv_n;
    const float var = psumsq * inv_n - mean * mean;
    const float rstd = rsqrtf(var + EPS);

    const size_t base = (size_t)blockIdx.x * (THREADS * FITERS);
    float acc = 0.0f;
#pragma unroll
    for (int i = 0; i < FITERS; ++i) {
        const size_t idx = base + i * THREADS + threadIdx.x;
        f32x4 tv = t[idx];
        f32x4 sv = __builtin_nontemporal_load(st + idx);
        float d0 = fabsf((tv.x - mean) * rstd - sv.x);
        float d1 = fabsf((tv.y - mean) * rstd - sv.y);
        float d2 = fabsf((tv.z - mean) * rstd - sv.z);
        float d3 = fabsf((tv.w - mean) * rstd - sv.w);
        acc += smooth_l1(d0) + smooth_l1(d1) + smooth_l1(d2) + smooth_l1(d3);
    }

    const int wid = threadIdx.x >> 6;
    acc = wave_reduce_sum(acc);
    __shared__ float sm[THREADS / 64];
    if (lane == 0) sm[wid] = acc;
    __syncthreads();
    if (threadIdx.x == 0)
        lpart[blockIdx.x] = sm[0] + sm[1] + sm[2] + sm[3];
}

__global__ __launch_bounds__(THREADS) void kd_final_kernel(
    const float* __restrict__ lpart, float* __restrict__ out) {
    float acc = 0.0f;
#pragma unroll
    for (int i = 0; i < FGRID / THREADS; ++i)  // 8
        acc += lpart[i * THREADS + threadIdx.x];
    const int lane = threadIdx.x & 63;
    const int wid = threadIdx.x >> 6;
    acc = wave_reduce_sum(acc);
    __shared__ float sm[THREADS / 64];
    if (lane == 0) sm[wid] = acc;
    __syncthreads();
    if (threadIdx.x == 0)
        out[0] = (sm[0] + sm[1] + sm[2] + sm[3]) * (1.0f / (float)SAMPLES);
}

extern "C" void kernel_launch(void* const* d_in, const int* in_sizes, int n_in,
                              void* d_out, int out_size, void* d_ws,
                              size_t ws_size, hipStream_t stream) {
    const f32x4* teacher = (const f32x4*)d_in[0];
    const f32x4* student = (const f32x4*)d_in[1];
    float* out = (float*)d_out;
    float* ws = (float*)d_ws;

    void* args[4] = {(void*)&teacher, (void*)&student, (void*)&ws, (void*)&out};
    hipError_t e = hipLaunchCooperativeKernel(
        (void*)kd_fused2_kernel, dim3(GRID2), dim3(THREADS), args, 0, stream);

    if (e != hipSuccess) {
        float* stats = ws;
        float* lpart = ws + 2 * FGRID;
        kd_stats_kernel<<<FGRID, THREADS, 0, stream>>>(teacher, stats);
        kd_loss_kernel<<<FGRID, THREADS, 0, stream>>>(teacher, student, stats, lpart);
        kd_final_kernel<<<1, THREADS, 0, stream>>>(lpart, out);
    }
}